// Round 1
// 222.275 us; speedup vs baseline: 1.0484x; 1.0484x over previous
//
#include <hip/hip_runtime.h>
#include <math.h>

#define DIM   1024
#define HEADS 16
#define DH    64
#define ROT   128
#define BATCH 2
#define SEQ   2048
#define ROWS  (BATCH*SEQ)        // 4096
#define PCOLS (DIM + 2*DH)       // 1152 = [q(1024) | k(64) | v(64)] per side
// 1/sqrt(128) * log2(e): scores arrive pre-scaled for exp2 in attn
#define ASCALE (0.08838834764831845f * 1.4426950408889634f)

typedef short bf16x8 __attribute__((ext_vector_type(8)));
typedef float f32x16 __attribute__((ext_vector_type(16)));
typedef unsigned u32x2 __attribute__((ext_vector_type(2)));

static __device__ __forceinline__ unsigned short f2bf(float f) {
    union { float f; unsigned u; } v; v.f = f;
    unsigned r = v.u + 0x7fffu + ((v.u >> 16) & 1u);   // RNE (no NaN inputs here)
    return (unsigned short)(r >> 16);
}
static __device__ __forceinline__ float bf2f(unsigned short u) {
    union { unsigned u; float f; } v; v.u = (unsigned)u << 16;
    return v.f;
}

#define GL2LDS(gp, lp) __builtin_amdgcn_global_load_lds(                    \
    (const __attribute__((address_space(1))) void*)(gp),                    \
    (__attribute__((address_space(3))) void*)(lp), 16, 0, 0)
#define CFENCE() asm volatile("" ::: "memory")
// s_waitcnt imm: vmcnt[3:0]|[15:14], expcnt[6:4], lgkmcnt[11:8]; others maxed
#define WAIT_VM8()  __builtin_amdgcn_s_waitcnt(0xF78)   // vmcnt(8)
#define WAIT_VM0()  __builtin_amdgcn_s_waitcnt(0xF70)   // vmcnt(0)

// ---------------------------------------------------------------------------
// Convert fp32 inputs -> bf16 staging buffers + rotary cos/sin table.
// ---------------------------------------------------------------------------
__global__ __launch_bounds__(256) void convert_kernel(
    const float* __restrict__ x, const float* __restrict__ a,
    const float* __restrict__ Wq_x, const float* __restrict__ Wkv_x,
    const float* __restrict__ Wq_a, const float* __restrict__ Wkv_a,
    unsigned short* __restrict__ xbf, unsigned short* __restrict__ wbf,
    float2* __restrict__ tbl)
{
    const int blk = blockIdx.x;
    const float LN1E4_64 = 0.14391156831213f;   // ln(10000)/64
    if (blk >= 2624) {                           // rotary table segment
        int local = blk - 2624;                  // 0..127
        int pos = local * 16 + (threadIdx.x >> 4);
        int i   = threadIdx.x & 15;
        #pragma unroll
        for (int j = 0; j < 4; j++) {
            int jd = i * 4 + j;
            float th = (float)pos * expf(-LN1E4_64 * (float)jd);
            float sn, cs; sincosf(th, &sn, &cs);
            tbl[pos * 64 + jd] = make_float2(cs, sn);
        }
        return;
    }
    const float* s; unsigned short* d; int seg0;
    if      (blk < 1024) { s = x;     d = xbf;           seg0 = 0;    }
    else if (blk < 2048) { s = a;     d = xbf + 4194304; seg0 = 1024; }
    else if (blk < 2304) { s = Wq_x;  d = wbf;           seg0 = 2048; }
    else if (blk < 2336) { s = Wkv_x; d = wbf + 1048576; seg0 = 2304; }
    else if (blk < 2592) { s = Wq_a;  d = wbf + 1179648; seg0 = 2336; }
    else                 { s = Wkv_a; d = wbf + 2228224; seg0 = 2592; }
    long lb = ((long)blk - seg0) * 1024;
    #pragma unroll
    for (int j = 0; j < 4; j++) {
        long idx = lb + j * 256 + threadIdx.x;
        float4 v = ((const float4*)s)[idx];
        ((ushort4*)d)[idx] = make_ushort4(f2bf(v.x), f2bf(v.y), f2bf(v.z), f2bf(v.w));
    }
}

// ---------------------------------------------------------------------------
// MFMA GEMM (bf16, 32x32x16) — unchanged from R2.
// ---------------------------------------------------------------------------
__global__ __launch_bounds__(256) void mfma_gemm_kernel(
    const unsigned short* __restrict__ xbf, const unsigned short* __restrict__ wbf,
    unsigned short* __restrict__ Pbf)
{
    const int mt = blockIdx.x, jt = blockIdx.y, side = blockIdx.z;
    const unsigned short* Ag = xbf + ((size_t)side * ROWS  + mt * 128) * DIM;
    const unsigned short* Bg = wbf + ((size_t)side * PCOLS + jt * 128) * DIM;
    unsigned short* Pp = Pbf + (size_t)side * ROWS * PCOLS;

    __shared__ __align__(16) unsigned short As[128 * 32];
    __shared__ __align__(16) unsigned short Bs[128 * 32];

    const int tid  = threadIdx.x;
    const int wave = tid >> 6, lane = tid & 63;
    const int m = lane & 31, hl = lane >> 5;
    const int wr = wave >> 1, wc = wave & 1;

    f32x16 acc[2][2];
    #pragma unroll
    for (int i2 = 0; i2 < 2; i2++)
        #pragma unroll
        for (int j2 = 0; j2 < 2; j2++) acc[i2][j2] = 0.0f;

    int sr[2], sg[2]; unsigned ldsb[2];
    #pragma unroll
    for (int it = 0; it < 2; it++) {
        int s = it * 256 + tid;
        sr[it] = s >> 2;
        sg[it] = (s & 3) ^ ((sr[it] >> 1) & 3);
        ldsb[it] = (unsigned)(it * 256 + wave * 64) * 16;
    }

    for (int k0 = 0; k0 < DIM; k0 += 32) {
        __syncthreads();
        #pragma unroll
        for (int it = 0; it < 2; it++) {
            GL2LDS(Ag + (size_t)sr[it] * DIM + k0 + sg[it] * 8, (char*)As + ldsb[it]);
            GL2LDS(Bg + (size_t)sr[it] * DIM + k0 + sg[it] * 8, (char*)Bs + ldsb[it]);
        }
        __syncthreads();
        #pragma unroll
        for (int kp = 0; kp < 2; kp++) {
            bf16x8 af[2], bff[2];
            #pragma unroll
            for (int t2 = 0; t2 < 2; t2++) {
                int ra = wr * 64 + t2 * 32 + m;
                int ga = (kp * 2 + hl) ^ ((ra >> 1) & 3);
                af[t2] = *(const bf16x8*)&As[ra * 32 + ga * 8];
                int rb = wc * 64 + t2 * 32 + m;
                int gb = (kp * 2 + hl) ^ ((rb >> 1) & 3);
                bff[t2] = *(const bf16x8*)&Bs[rb * 32 + gb * 8];
            }
            #pragma unroll
            for (int i2 = 0; i2 < 2; i2++)
                #pragma unroll
                for (int j2 = 0; j2 < 2; j2++)
                    acc[i2][j2] = __builtin_amdgcn_mfma_f32_32x32x16_bf16(
                        af[i2], bff[j2], acc[i2][j2], 0, 0, 0);
        }
    }

    const int m0 = mt * 128 + wr * 64;
    const int n0 = jt * 128 + wc * 64;
    #pragma unroll
    for (int i2 = 0; i2 < 2; i2++)
        #pragma unroll
        for (int j2 = 0; j2 < 2; j2++)
            #pragma unroll
            for (int r = 0; r < 16; r++) {
                int row = m0 + i2 * 32 + (r & 3) + 8 * (r >> 2) + 4 * hl;
                int col = n0 + j2 * 32 + m;
                Pp[(size_t)row * PCOLS + col] = f2bf(acc[i2][j2][r]);
            }
}

// ---------------------------------------------------------------------------
// Fuse: l2norm + scale + concat + rotary (bf16 P in, table-driven rotary).
// Q additionally carries 1/sqrt(128)*log2(e) so attn can use raw v_exp_f32.
// ---------------------------------------------------------------------------
__global__ __launch_bounds__(256) void fuse_kernel(
    const unsigned short* __restrict__ Pbf,
    const float* __restrict__ qx_scale, const float* __restrict__ qa_scale,
    const float* __restrict__ kx_scale, const float* __restrict__ ka_scale,
    const float2* __restrict__ tbl,
    unsigned short* __restrict__ qbuf, unsigned short* __restrict__ kbuf,
    unsigned short* __restrict__ vbufT)
{
    const int row = blockIdx.x;            // b*SEQ + pos
    const int b = row >> 11, pos = row & 2047;
    const unsigned short* Px = Pbf + (size_t)row * PCOLS;
    const unsigned short* Pa = Pbf + (size_t)ROWS * PCOLS + (size_t)row * PCOLS;
    const int tid = threadIdx.x;
    const int h = tid >> 4, i = tid & 15;
    const float2* tb = tbl + pos * 64;

    // ---- Q ----
    ushort4 xu = *(const ushort4*)(Px + h * DH + i * 4);
    ushort4 au = *(const ushort4*)(Pa + h * DH + i * 4);
    float xr[4] = {bf2f(xu.x), bf2f(xu.y), bf2f(xu.z), bf2f(xu.w)};
    float ar[4] = {bf2f(au.x), bf2f(au.y), bf2f(au.z), bf2f(au.w)};
    float ssx = xr[0]*xr[0] + xr[1]*xr[1] + xr[2]*xr[2] + xr[3]*xr[3];
    float ssa = ar[0]*ar[0] + ar[1]*ar[1] + ar[2]*ar[2] + ar[3]*ar[3];
    #pragma unroll
    for (int off = 1; off < 16; off <<= 1) {
        ssx += __shfl_xor(ssx, off, 16);
        ssa += __shfl_xor(ssa, off, 16);
    }
    float inx = 1.0f / fmaxf(sqrtf(ssx), 1e-12f);
    float ina = 1.0f / fmaxf(sqrtf(ssa), 1e-12f);
    unsigned short qlo[4], qhi[4];
    #pragma unroll
    for (int j = 0; j < 4; j++) {
        int jd = i * 4 + j;
        float qx = xr[j] * inx * qx_scale[h * DH + jd];
        float qa = ar[j] * ina * qa_scale[h * DH + jd];
        float2 cssn = tb[jd];
        qlo[j] = f2bf((qx * cssn.x - qa * cssn.y) * ASCALE);
        qhi[j] = f2bf((qa * cssn.x + qx * cssn.y) * ASCALE);
    }
    unsigned short* qp = qbuf + (((size_t)(b * HEADS + h)) * SEQ + pos) * ROT;
    *(ushort4*)(qp + i * 4)      = make_ushort4(qlo[0], qlo[1], qlo[2], qlo[3]);
    *(ushort4*)(qp + DH + i * 4) = make_ushort4(qhi[0], qhi[1], qhi[2], qhi[3]);

    // ---- K ----
    if (tid < 16) {
        ushort4 kxu = *(const ushort4*)(Px + DIM + tid * 4);
        ushort4 kau = *(const ushort4*)(Pa + DIM + tid * 4);
        float kxr[4] = {bf2f(kxu.x), bf2f(kxu.y), bf2f(kxu.z), bf2f(kxu.w)};
        float kar[4] = {bf2f(kau.x), bf2f(kau.y), bf2f(kau.z), bf2f(kau.w)};
        float sx = kxr[0]*kxr[0] + kxr[1]*kxr[1] + kxr[2]*kxr[2] + kxr[3]*kxr[3];
        float sa = kar[0]*kar[0] + kar[1]*kar[1] + kar[2]*kar[2] + kar[3]*kar[3];
        #pragma unroll
        for (int off = 1; off < 16; off <<= 1) {
            sx += __shfl_xor(sx, off, 16);
            sa += __shfl_xor(sa, off, 16);
        }
        float ikx = 1.0f / fmaxf(sqrtf(sx), 1e-12f);
        float ika = 1.0f / fmaxf(sqrtf(sa), 1e-12f);
        unsigned short klo[4], khi[4];
        #pragma unroll
        for (int j = 0; j < 4; j++) {
            int jd = tid * 4 + j;
            float kx = kxr[j] * ikx * kx_scale[jd];
            float ka = kar[j] * ika * ka_scale[jd];
            float2 cssn = tb[jd];
            klo[j] = f2bf(kx * cssn.x - ka * cssn.y);
            khi[j] = f2bf(ka * cssn.x + kx * cssn.y);
        }
        unsigned short* kp = kbuf + ((size_t)b * SEQ + pos) * ROT;
        *(ushort4*)(kp + tid * 4)      = make_ushort4(klo[0], klo[1], klo[2], klo[3]);
        *(ushort4*)(kp + DH + tid * 4) = make_ushort4(khi[0], khi[1], khi[2], khi[3]);
    }
    // ---- V (transposed store, exact bf16 copy) ----
    if (tid >= 64 && tid < 96) {
        int iv = tid - 64;
        unsigned short* vT = vbufT + (size_t)b * ROT * SEQ + pos;
        const unsigned short* src; int d;
        if (iv < 16) { src = Px + DIM + DH + iv * 4;        d = iv * 4;              }
        else         { src = Pa + DIM + DH + (iv - 16) * 4; d = DH + (iv - 16) * 4;  }
        ushort4 v4 = *(const ushort4*)src;
        vT[(size_t)(d + 0) * SEQ] = v4.x;
        vT[(size_t)(d + 1) * SEQ] = v4.y;
        vT[(size_t)(d + 2) * SEQ] = v4.z;
        vT[(size_t)(d + 3) * SEQ] = v4.w;
    }
}

// ---------------------------------------------------------------------------
// MFMA flash attention (bf16, 32x32x16), double-buffered pipeline.
// R3 changes vs R2:
//  * V swizzle (d&7) -> ((d>>2)&7): kills the 4-way LDS bank conflict on the
//    PV ds_read_b128 (lanes {m,m+8,m+16,m+24} previously aliased mod 512B).
//    Applied to BOTH staging source and read (both-sides-or-neither).
//  * P-repack via v_cvt_pk_bf16_f32 + v_permlane32_swap_b32 (T12): replaces
//    ~100 VALU ops/kg of shfl_xor+cndmask+bit-twiddle f2bf with 12 ops.
//  * exp2 instead of expf: log2(e) folded into Q's ASCALE in fuse_kernel.
//  * s_setprio(1) around MFMA clusters (T5; attn regime, +4-7% per m191).
// ---------------------------------------------------------------------------
__global__ __launch_bounds__(256, 2) void attn_kernel(
    const unsigned short* __restrict__ qbuf,
    const unsigned short* __restrict__ kbuf,
    const unsigned short* __restrict__ vbufT,
    float* __restrict__ out)
{
    const int qb = blockIdx.x, h = blockIdx.y, b = blockIdx.z;
    __shared__ __align__(16) unsigned short Ks[2][64 * 128];   // 2x16 KB
    __shared__ __align__(16) unsigned short Vs[2][128 * 64];   // 2x16 KB
    const int tid  = threadIdx.x;
    const int wave = tid >> 6, lane = tid & 63;
    const int m = lane & 31, hl = lane >> 5;
    const int q0 = qb * 128 + wave * 32;

    // Q resident (B-frag): chunk c covers d = c*16 + hl*8 + j
    bf16x8 qf[8];
    {
        const unsigned short* qp = qbuf + (((size_t)(b * HEADS + h)) * SEQ + q0 + m) * ROT + hl * 8;
        #pragma unroll
        for (int c = 0; c < 8; c++) qf[c] = *(const bf16x8*)(qp + c * 16);
    }

    f32x16 oacc[4];
    #pragma unroll
    for (int dt = 0; dt < 4; dt++) oacc[dt] = 0.0f;
    float lsum = 0.f;

    const unsigned short* kb_ = kbuf  + (size_t)b * SEQ * ROT;
    const unsigned short* vb_ = vbufT + (size_t)b * ROT * SEQ;

    // per-thread staging addresses (swizzle folded into the global source)
    const unsigned short* ksrc[4];
    const unsigned short* vsrc[4];
    unsigned ldsoff[4];
    #pragma unroll
    for (int i = 0; i < 4; i++) {
        int fg = i * 256 + tid;
        int krow = fg >> 4, kg = fg & 15;                 // K: 64 rows x 16 granules
        ksrc[i] = kb_ + (size_t)krow * ROT + ((kg ^ (krow & 15)) << 3);
        int rv = fg >> 3, gv = fg & 7;                    // V^T: 128 rows x 8 granules
        vsrc[i] = vb_ + (size_t)rv * SEQ + ((gv ^ ((rv >> 2) & 7)) << 3);
        ldsoff[i] = (unsigned)(i * 256 + wave * 64) * 16; // bytes, wave-uniform base
    }

    // stage tile 0 into buffer 0
    #pragma unroll
    for (int i = 0; i < 4; i++) {
        GL2LDS(ksrc[i], (char*)Ks[0] + ldsoff[i]);
        GL2LDS(vsrc[i], (char*)Vs[0] + ldsoff[i]);
    }

    for (int t = 0; t < 32; t++) {
        const int buf = t & 1;
        if (t < 31) {                         // prefetch t+1 into alternate buffer
            #pragma unroll
            for (int i = 0; i < 4; i++) {
                GL2LDS(ksrc[i] + (size_t)(t + 1) * 64 * ROT, (char*)Ks[buf ^ 1] + ldsoff[i]);
                GL2LDS(vsrc[i] + (t + 1) * 64,               (char*)Vs[buf ^ 1] + ldsoff[i]);
            }
        }
        CFENCE();
        if (t < 31) WAIT_VM8(); else WAIT_VM0();   // tile t's 8 loads are the oldest
        __builtin_amdgcn_s_barrier();
        CFENCE();

        #pragma unroll
        for (int kg = 0; kg < 2; kg++) {
            // S^T tile: 32 keys x 32 qrows
            f32x16 st = 0.0f;
            __builtin_amdgcn_s_setprio(1);
            #pragma unroll
            for (int c = 0; c < 8; c++) {
                bf16x8 af = *(const bf16x8*)&Ks[buf][(kg * 32 + m) * 128 +
                                                     (((2 * c + hl) ^ (m & 15)) << 3)];
                st = __builtin_amdgcn_mfma_f32_32x32x16_bf16(af, qf[c], st, 0, 0, 0);
            }
            __builtin_amdgcn_s_setprio(0);

            // p[r] = exp2(st[r]); log2(e) was folded into Q upstream.
            float p[16];
            #pragma unroll
            for (int r = 0; r < 16; r++) { p[r] = __builtin_amdgcn_exp2f(st[r]); lsum += p[r]; }

            // PV over two 16-key windows; P-repack: cvt_pk + permlane32_swap.
            // Own-half words X=(p[8w+0..3]), Y=(p[8w+4..7]); after swap:
            //   s0 = {X.lo | Y.lo}  -> aP keys {0,1}/{8,9}   (per hl half)
            //   s1 = {X.hi | Y.hi}  -> aP keys {4,5}/{12,13}
            #pragma unroll
            for (int w = 0; w < 2; w++) {
                unsigned pk0, pk1, pk2, pk3;
                asm("v_cvt_pk_bf16_f32 %0, %1, %2" : "=v"(pk0) : "v"(p[8*w+0]), "v"(p[8*w+1]));
                asm("v_cvt_pk_bf16_f32 %0, %1, %2" : "=v"(pk1) : "v"(p[8*w+2]), "v"(p[8*w+3]));
                asm("v_cvt_pk_bf16_f32 %0, %1, %2" : "=v"(pk2) : "v"(p[8*w+4]), "v"(p[8*w+5]));
                asm("v_cvt_pk_bf16_f32 %0, %1, %2" : "=v"(pk3) : "v"(p[8*w+6]), "v"(p[8*w+7]));
                u32x2 s0 = __builtin_amdgcn_permlane32_swap(pk0, pk2, false, false);
                u32x2 s1 = __builtin_amdgcn_permlane32_swap(pk1, pk3, false, false);
                union { unsigned u[4]; bf16x8 v; } apu;
                apu.u[0] = s0[0]; apu.u[1] = s1[0]; apu.u[2] = s0[1]; apu.u[3] = s1[1];
                bf16x8 aP = apu.v;

                __builtin_amdgcn_s_setprio(1);
                #pragma unroll
                for (int dt = 0; dt < 4; dt++) {
                    int d = dt * 32 + m;
                    bf16x8 vf = *(const bf16x8*)&Vs[buf][d * 64 +
                                 (((kg * 4 + w * 2 + hl) ^ ((d >> 2) & 7)) << 3)];
                    oacc[dt] = __builtin_amdgcn_mfma_f32_32x32x16_bf16(aP, vf, oacc[dt], 0, 0, 0);
                }
                __builtin_amdgcn_s_setprio(0);
            }
        }

        CFENCE();
        __builtin_amdgcn_s_barrier();    // protect buf from t+2's prefetch overwrite
        CFENCE();
    }

    lsum += __shfl_xor(lsum, 32);    // add other half-lane's keys
    float* ob = out + ((size_t)(b * SEQ + q0)) * (HEADS * ROT) + h * ROT + m;
    #pragma unroll
    for (int r = 0; r < 16; r++) {
        int qrow = (r & 3) + 8 * (r >> 2) + 4 * hl;
        float linv = 1.0f / __shfl(lsum, qrow);
        float* orow = ob + (size_t)qrow * (HEADS * ROT);
        #pragma unroll
        for (int dt = 0; dt < 4; dt++) orow[dt * 32] = oacc[dt][r] * linv;
    }
}

// ---------------------------------------------------------------------------
extern "C" void kernel_launch(void* const* d_in, const int* in_sizes, int n_in,
                              void* d_out, int out_size, void* d_ws, size_t ws_size,
                              hipStream_t stream) {
    (void)in_sizes; (void)n_in; (void)out_size; (void)ws_size;
    const float* x        = (const float*)d_in[0];
    const float* a        = (const float*)d_in[1];
    const float* Wq_x     = (const float*)d_in[2];
    const float* Wkv_x    = (const float*)d_in[3];
    const float* Wq_a     = (const float*)d_in[4];
    const float* Wkv_a    = (const float*)d_in[5];
    const float* qx_scale = (const float*)d_in[6];
    const float* qa_scale = (const float*)d_in[7];
    const float* kx_scale = (const float*)d_in[8];
    const float* ka_scale = (const float*)d_in[9];
    float* out = (float*)d_out;

    unsigned short* Pbf   = (unsigned short*)d_ws;
    unsigned short* qbuf  = Pbf   + (size_t)2 * ROWS * PCOLS;
    unsigned short* kbuf  = qbuf  + (size_t)BATCH * HEADS * SEQ * ROT;
    unsigned short* vbufT = kbuf  + (size_t)BATCH * SEQ * ROT;
    unsigned short* xbf   = vbufT + (size_t)BATCH * SEQ * ROT;
    unsigned short* wbf   = xbf   + (size_t)2 * ROWS * DIM;
    float2*         tbl   = (float2*)(wbf + (size_t)2 * PCOLS * DIM);

    convert_kernel<<<dim3(2752), 256, 0, stream>>>(x, a, Wq_x, Wkv_x, Wq_a, Wkv_a,
                                                   xbf, wbf, tbl);
    mfma_gemm_kernel<<<dim3(32, 9, 2), 256, 0, stream>>>(xbf, wbf, Pbf);
    fuse_kernel<<<dim3(ROWS), 256, 0, stream>>>(Pbf, qx_scale, qa_scale, kx_scale, ka_scale,
                                                tbl, qbuf, kbuf, vbufT);
    attn_kernel<<<dim3(SEQ / 128, HEADS, BATCH), 256, 0, stream>>>(qbuf, kbuf, vbufT, out);
}

// Round 2
// 212.619 us; speedup vs baseline: 1.0960x; 1.0454x over previous
//
#include <hip/hip_runtime.h>
#include <math.h>

#define DIM   1024
#define HEADS 16
#define DH    64
#define ROT   128
#define BATCH 2
#define SEQ   2048
#define ROWS  (BATCH*SEQ)        // 4096
#define PCOLS (DIM + 2*DH)       // 1152 = [q(1024) | k(64) | v(64)] per side
// 1/sqrt(128) * log2(e): scores arrive pre-scaled for exp2 in attn
#define ASCALE (0.08838834764831845f * 1.4426950408889634f)

typedef short bf16x8 __attribute__((ext_vector_type(8)));
typedef float f32x16 __attribute__((ext_vector_type(16)));
typedef unsigned u32x2 __attribute__((ext_vector_type(2)));

static __device__ __forceinline__ unsigned short f2bf(float f) {
    union { float f; unsigned u; } v; v.f = f;
    unsigned r = v.u + 0x7fffu + ((v.u >> 16) & 1u);   // RNE (no NaN inputs here)
    return (unsigned short)(r >> 16);
}
static __device__ __forceinline__ float bf2f(unsigned short u) {
    union { unsigned u; float f; } v; v.u = (unsigned)u << 16;
    return v.f;
}

#define GL2LDS(gp, lp) __builtin_amdgcn_global_load_lds(                    \
    (const __attribute__((address_space(1))) void*)(gp),                    \
    (__attribute__((address_space(3))) void*)(lp), 16, 0, 0)
#define CFENCE() asm volatile("" ::: "memory")
// s_waitcnt imm: vmcnt[3:0]|[15:14], expcnt[6:4], lgkmcnt[11:8]; others maxed
#define WAIT_VM8()  __builtin_amdgcn_s_waitcnt(0xF78)   // vmcnt(8)
#define WAIT_VM0()  __builtin_amdgcn_s_waitcnt(0xF70)   // vmcnt(0)

// ---------------------------------------------------------------------------
// Convert fp32 inputs -> bf16 staging buffers + rotary cos/sin table.
// ---------------------------------------------------------------------------
__global__ __launch_bounds__(256) void convert_kernel(
    const float* __restrict__ x, const float* __restrict__ a,
    const float* __restrict__ Wq_x, const float* __restrict__ Wkv_x,
    const float* __restrict__ Wq_a, const float* __restrict__ Wkv_a,
    unsigned short* __restrict__ xbf, unsigned short* __restrict__ wbf,
    float2* __restrict__ tbl)
{
    const int blk = blockIdx.x;
    const float LN1E4_64 = 0.14391156831213f;   // ln(10000)/64
    if (blk >= 2624) {                           // rotary table segment
        int local = blk - 2624;                  // 0..127
        int pos = local * 16 + (threadIdx.x >> 4);
        int i   = threadIdx.x & 15;
        #pragma unroll
        for (int j = 0; j < 4; j++) {
            int jd = i * 4 + j;
            float th = (float)pos * expf(-LN1E4_64 * (float)jd);
            float sn, cs; sincosf(th, &sn, &cs);
            tbl[pos * 64 + jd] = make_float2(cs, sn);
        }
        return;
    }
    const float* s; unsigned short* d; int seg0;
    if      (blk < 1024) { s = x;     d = xbf;           seg0 = 0;    }
    else if (blk < 2048) { s = a;     d = xbf + 4194304; seg0 = 1024; }
    else if (blk < 2304) { s = Wq_x;  d = wbf;           seg0 = 2048; }
    else if (blk < 2336) { s = Wkv_x; d = wbf + 1048576; seg0 = 2304; }
    else if (blk < 2592) { s = Wq_a;  d = wbf + 1179648; seg0 = 2336; }
    else                 { s = Wkv_a; d = wbf + 2228224; seg0 = 2592; }
    long lb = ((long)blk - seg0) * 1024;
    #pragma unroll
    for (int j = 0; j < 4; j++) {
        long idx = lb + j * 256 + threadIdx.x;
        float4 v = ((const float4*)s)[idx];
        ((ushort4*)d)[idx] = make_ushort4(f2bf(v.x), f2bf(v.y), f2bf(v.z), f2bf(v.w));
    }
}

// ---------------------------------------------------------------------------
// MFMA GEMM (bf16, 32x32x16) — unchanged.
// ---------------------------------------------------------------------------
__global__ __launch_bounds__(256) void mfma_gemm_kernel(
    const unsigned short* __restrict__ xbf, const unsigned short* __restrict__ wbf,
    unsigned short* __restrict__ Pbf)
{
    const int mt = blockIdx.x, jt = blockIdx.y, side = blockIdx.z;
    const unsigned short* Ag = xbf + ((size_t)side * ROWS  + mt * 128) * DIM;
    const unsigned short* Bg = wbf + ((size_t)side * PCOLS + jt * 128) * DIM;
    unsigned short* Pp = Pbf + (size_t)side * ROWS * PCOLS;

    __shared__ __align__(16) unsigned short As[128 * 32];
    __shared__ __align__(16) unsigned short Bs[128 * 32];

    const int tid  = threadIdx.x;
    const int wave = tid >> 6, lane = tid & 63;
    const int m = lane & 31, hl = lane >> 5;
    const int wr = wave >> 1, wc = wave & 1;

    f32x16 acc[2][2];
    #pragma unroll
    for (int i2 = 0; i2 < 2; i2++)
        #pragma unroll
        for (int j2 = 0; j2 < 2; j2++) acc[i2][j2] = 0.0f;

    int sr[2], sg[2]; unsigned ldsb[2];
    #pragma unroll
    for (int it = 0; it < 2; it++) {
        int s = it * 256 + tid;
        sr[it] = s >> 2;
        sg[it] = (s & 3) ^ ((sr[it] >> 1) & 3);
        ldsb[it] = (unsigned)(it * 256 + wave * 64) * 16;
    }

    for (int k0 = 0; k0 < DIM; k0 += 32) {
        __syncthreads();
        #pragma unroll
        for (int it = 0; it < 2; it++) {
            GL2LDS(Ag + (size_t)sr[it] * DIM + k0 + sg[it] * 8, (char*)As + ldsb[it]);
            GL2LDS(Bg + (size_t)sr[it] * DIM + k0 + sg[it] * 8, (char*)Bs + ldsb[it]);
        }
        __syncthreads();
        #pragma unroll
        for (int kp = 0; kp < 2; kp++) {
            bf16x8 af[2], bff[2];
            #pragma unroll
            for (int t2 = 0; t2 < 2; t2++) {
                int ra = wr * 64 + t2 * 32 + m;
                int ga = (kp * 2 + hl) ^ ((ra >> 1) & 3);
                af[t2] = *(const bf16x8*)&As[ra * 32 + ga * 8];
                int rb = wc * 64 + t2 * 32 + m;
                int gb = (kp * 2 + hl) ^ ((rb >> 1) & 3);
                bff[t2] = *(const bf16x8*)&Bs[rb * 32 + gb * 8];
            }
            #pragma unroll
            for (int i2 = 0; i2 < 2; i2++)
                #pragma unroll
                for (int j2 = 0; j2 < 2; j2++)
                    acc[i2][j2] = __builtin_amdgcn_mfma_f32_32x32x16_bf16(
                        af[i2], bff[j2], acc[i2][j2], 0, 0, 0);
        }
    }

    const int m0 = mt * 128 + wr * 64;
    const int n0 = jt * 128 + wc * 64;
    #pragma unroll
    for (int i2 = 0; i2 < 2; i2++)
        #pragma unroll
        for (int j2 = 0; j2 < 2; j2++)
            #pragma unroll
            for (int r = 0; r < 16; r++) {
                int row = m0 + i2 * 32 + (r & 3) + 8 * (r >> 2) + 4 * hl;
                int col = n0 + j2 * 32 + m;
                Pp[(size_t)row * PCOLS + col] = f2bf(acc[i2][j2][r]);
            }
}

// ---------------------------------------------------------------------------
// Fuse: l2norm + scale + concat + rotary (bf16 P in, table-driven rotary).
// Q additionally carries 1/sqrt(128)*log2(e) so attn can use raw v_exp_f32.
// ---------------------------------------------------------------------------
__global__ __launch_bounds__(256) void fuse_kernel(
    const unsigned short* __restrict__ Pbf,
    const float* __restrict__ qx_scale, const float* __restrict__ qa_scale,
    const float* __restrict__ kx_scale, const float* __restrict__ ka_scale,
    const float2* __restrict__ tbl,
    unsigned short* __restrict__ qbuf, unsigned short* __restrict__ kbuf,
    unsigned short* __restrict__ vbufT)
{
    const int row = blockIdx.x;            // b*SEQ + pos
    const int b = row >> 11, pos = row & 2047;
    const unsigned short* Px = Pbf + (size_t)row * PCOLS;
    const unsigned short* Pa = Pbf + (size_t)ROWS * PCOLS + (size_t)row * PCOLS;
    const int tid = threadIdx.x;
    const int h = tid >> 4, i = tid & 15;
    const float2* tb = tbl + pos * 64;

    // ---- Q ----
    ushort4 xu = *(const ushort4*)(Px + h * DH + i * 4);
    ushort4 au = *(const ushort4*)(Pa + h * DH + i * 4);
    float xr[4] = {bf2f(xu.x), bf2f(xu.y), bf2f(xu.z), bf2f(xu.w)};
    float ar[4] = {bf2f(au.x), bf2f(au.y), bf2f(au.z), bf2f(au.w)};
    float ssx = xr[0]*xr[0] + xr[1]*xr[1] + xr[2]*xr[2] + xr[3]*xr[3];
    float ssa = ar[0]*ar[0] + ar[1]*ar[1] + ar[2]*ar[2] + ar[3]*ar[3];
    #pragma unroll
    for (int off = 1; off < 16; off <<= 1) {
        ssx += __shfl_xor(ssx, off, 16);
        ssa += __shfl_xor(ssa, off, 16);
    }
    float inx = 1.0f / fmaxf(sqrtf(ssx), 1e-12f);
    float ina = 1.0f / fmaxf(sqrtf(ssa), 1e-12f);
    unsigned short qlo[4], qhi[4];
    #pragma unroll
    for (int j = 0; j < 4; j++) {
        int jd = i * 4 + j;
        float qx = xr[j] * inx * qx_scale[h * DH + jd];
        float qa = ar[j] * ina * qa_scale[h * DH + jd];
        float2 cssn = tb[jd];
        qlo[j] = f2bf((qx * cssn.x - qa * cssn.y) * ASCALE);
        qhi[j] = f2bf((qa * cssn.x + qx * cssn.y) * ASCALE);
    }
    unsigned short* qp = qbuf + (((size_t)(b * HEADS + h)) * SEQ + pos) * ROT;
    *(ushort4*)(qp + i * 4)      = make_ushort4(qlo[0], qlo[1], qlo[2], qlo[3]);
    *(ushort4*)(qp + DH + i * 4) = make_ushort4(qhi[0], qhi[1], qhi[2], qhi[3]);

    // ---- K ----
    if (tid < 16) {
        ushort4 kxu = *(const ushort4*)(Px + DIM + tid * 4);
        ushort4 kau = *(const ushort4*)(Pa + DIM + tid * 4);
        float kxr[4] = {bf2f(kxu.x), bf2f(kxu.y), bf2f(kxu.z), bf2f(kxu.w)};
        float kar[4] = {bf2f(kau.x), bf2f(kau.y), bf2f(kau.z), bf2f(kau.w)};
        float sx = kxr[0]*kxr[0] + kxr[1]*kxr[1] + kxr[2]*kxr[2] + kxr[3]*kxr[3];
        float sa = kar[0]*kar[0] + kar[1]*kar[1] + kar[2]*kar[2] + kar[3]*kar[3];
        #pragma unroll
        for (int off = 1; off < 16; off <<= 1) {
            sx += __shfl_xor(sx, off, 16);
            sa += __shfl_xor(sa, off, 16);
        }
        float ikx = 1.0f / fmaxf(sqrtf(sx), 1e-12f);
        float ika = 1.0f / fmaxf(sqrtf(sa), 1e-12f);
        unsigned short klo[4], khi[4];
        #pragma unroll
        for (int j = 0; j < 4; j++) {
            int jd = tid * 4 + j;
            float kx = kxr[j] * ikx * kx_scale[jd];
            float ka = kar[j] * ika * ka_scale[jd];
            float2 cssn = tb[jd];
            klo[j] = f2bf(kx * cssn.x - ka * cssn.y);
            khi[j] = f2bf(ka * cssn.x + kx * cssn.y);
        }
        unsigned short* kp = kbuf + ((size_t)b * SEQ + pos) * ROT;
        *(ushort4*)(kp + tid * 4)      = make_ushort4(klo[0], klo[1], klo[2], klo[3]);
        *(ushort4*)(kp + DH + tid * 4) = make_ushort4(khi[0], khi[1], khi[2], khi[3]);
    }
    // ---- V (transposed store, exact bf16 copy) ----
    if (tid >= 64 && tid < 96) {
        int iv = tid - 64;
        unsigned short* vT = vbufT + (size_t)b * ROT * SEQ + pos;
        const unsigned short* src; int d;
        if (iv < 16) { src = Px + DIM + DH + iv * 4;        d = iv * 4;              }
        else         { src = Pa + DIM + DH + (iv - 16) * 4; d = DH + (iv - 16) * 4;  }
        ushort4 v4 = *(const ushort4*)src;
        vT[(size_t)(d + 0) * SEQ] = v4.x;
        vT[(size_t)(d + 1) * SEQ] = v4.y;
        vT[(size_t)(d + 2) * SEQ] = v4.z;
        vT[(size_t)(d + 3) * SEQ] = v4.w;
    }
}

// ---------------------------------------------------------------------------
// MFMA flash attention (bf16, 32x32x16), double-buffered pipeline.
// R4 changes vs R3 (attn is wave-serial-latency bound at 2 waves/SIMD):
//  * t-loop unrolled x2 -> compile-time buf.  All 32 LDS reads become
//    ds_read_b128 with immediate offsets off 12 precomputed per-lane base
//    registers (koff[8], voff[2][2]; V's XOR term (d>>2)&7 == (m>>2)&7 is
//    dt-independent so dt*4096 and buf*16384 fold into offset:imm).
//  * QK for BOTH kg issued up front (st0,st1 live): exp/repack(kg0) issues
//    under QK(kg1)'s matrix-pipe shadow, exp/repack(kg1) under PV(kg0)'s.
//    m119: chained MFMA runs at full rate, so the 16-deep burst is free.
//  * setprio pairs reduced 6 -> 3 per tile (fewer scheduling fences).
// Layout of smem (bytes): K0@0, K1@16384, V0@32768, V1@49152.
// ---------------------------------------------------------------------------
__global__ __launch_bounds__(256, 2) void attn_kernel(
    const unsigned short* __restrict__ qbuf,
    const unsigned short* __restrict__ kbuf,
    const unsigned short* __restrict__ vbufT,
    float* __restrict__ out)
{
    const int qb = blockIdx.x, h = blockIdx.y, b = blockIdx.z;
    __shared__ __align__(16) unsigned short smem[32768];   // 64 KB
    const char* sc = (const char*)smem;
    const int tid  = threadIdx.x;
    const int wave = tid >> 6, lane = tid & 63;
    const int m = lane & 31, hl = lane >> 5;
    const int q0 = qb * 128 + wave * 32;

    // Q resident (B-frag): chunk c covers d = c*16 + hl*8 + j
    bf16x8 qf[8];
    {
        const unsigned short* qp = qbuf + (((size_t)(b * HEADS + h)) * SEQ + q0 + m) * ROT + hl * 8;
        #pragma unroll
        for (int c = 0; c < 8; c++) qf[c] = *(const bf16x8*)(qp + c * 16);
    }

    f32x16 oacc[4];
    #pragma unroll
    for (int dt = 0; dt < 4; dt++) oacc[dt] = 0.0f;
    float lsum = 0.f;

    // Precomputed per-lane LDS byte offsets (buf=0, kg=0, dt=0 bases).
    unsigned koff[8];
    #pragma unroll
    for (int c = 0; c < 8; c++)
        koff[c] = (unsigned)(m * 256 + (((2 * c + hl) ^ (m & 15)) << 4));
    unsigned voff[2][2];
    #pragma unroll
    for (int kg = 0; kg < 2; kg++)
        #pragma unroll
        for (int w = 0; w < 2; w++)
            voff[kg][w] = (unsigned)(32768 + m * 128 +
                                     (((kg * 4 + w * 2 + hl) ^ ((m >> 2) & 7)) << 4));

    const unsigned short* kb_ = kbuf  + (size_t)b * SEQ * ROT;
    const unsigned short* vb_ = vbufT + (size_t)b * ROT * SEQ;

    // per-thread staging addresses (swizzle folded into the global source)
    const unsigned short* ksrc[4];
    const unsigned short* vsrc[4];
    unsigned ldst[4];
    #pragma unroll
    for (int i = 0; i < 4; i++) {
        int fg = i * 256 + tid;
        int krow = fg >> 4, kgr = fg & 15;                // K: 64 rows x 16 granules
        ksrc[i] = kb_ + (size_t)krow * ROT + ((kgr ^ (krow & 15)) << 3);
        int rv = fg >> 3, gv = fg & 7;                    // V^T: 128 rows x 8 granules
        vsrc[i] = vb_ + (size_t)rv * SEQ + ((gv ^ ((rv >> 2) & 7)) << 3);
        ldst[i] = (unsigned)(i * 256 + wave * 64) * 16;   // bytes, wave-uniform base
    }

    // stage tile 0 into buffer 0
    #pragma unroll
    for (int i = 0; i < 4; i++) {
        GL2LDS(ksrc[i], sc + ldst[i]);
        GL2LDS(vsrc[i], sc + 32768 + ldst[i]);
    }

#define ATTN_TILE(BUF, T)                                                            \
  {                                                                                  \
    if ((T) < 31) {                        /* prefetch T+1 into alternate buffer */  \
      _Pragma("unroll")                                                              \
      for (int i = 0; i < 4; i++) {                                                  \
        GL2LDS(ksrc[i] + (size_t)((T) + 1) * 64 * ROT,                               \
               sc + ((BUF) ^ 1) * 16384 + ldst[i]);                                  \
        GL2LDS(vsrc[i] + ((T) + 1) * 64,                                             \
               sc + 32768 + ((BUF) ^ 1) * 16384 + ldst[i]);                          \
      }                                                                              \
    }                                                                                \
    CFENCE();                                                                        \
    if ((T) < 31) WAIT_VM8(); else WAIT_VM0();  /* tile T's 8 loads are oldest */    \
    __builtin_amdgcn_s_barrier();                                                    \
    CFENCE();                                                                        \
    f32x16 st0 = 0.0f, st1 = 0.0f;                                                   \
    __builtin_amdgcn_s_setprio(1);                                                   \
    _Pragma("unroll")                                                                \
    for (int c = 0; c < 8; c++) {                                                    \
      bf16x8 a0 = *(const bf16x8*)(sc + (BUF) * 16384 + koff[c]);                    \
      st0 = __builtin_amdgcn_mfma_f32_32x32x16_bf16(a0, qf[c], st0, 0, 0, 0);        \
    }                                                                                \
    _Pragma("unroll")                                                                \
    for (int c = 0; c < 8; c++) {                                                    \
      bf16x8 a1 = *(const bf16x8*)(sc + (BUF) * 16384 + 8192 + koff[c]);             \
      st1 = __builtin_amdgcn_mfma_f32_32x32x16_bf16(a1, qf[c], st1, 0, 0, 0);        \
    }                                                                                \
    __builtin_amdgcn_s_setprio(0);                                                   \
    _Pragma("unroll")                                                                \
    for (int kg = 0; kg < 2; kg++) {                                                 \
      float p[16];                                                                   \
      _Pragma("unroll")                                                              \
      for (int r = 0; r < 16; r++) {                                                 \
        float sv = kg ? st1[r] : st0[r];                                             \
        p[r] = __builtin_amdgcn_exp2f(sv); lsum += p[r];                             \
      }                                                                              \
      __builtin_amdgcn_s_setprio(1);                                                 \
      _Pragma("unroll")                                                              \
      for (int w = 0; w < 2; w++) {                                                  \
        unsigned pk0, pk1, pk2, pk3;                                                 \
        asm("v_cvt_pk_bf16_f32 %0, %1, %2" : "=v"(pk0) : "v"(p[8*w+0]), "v"(p[8*w+1])); \
        asm("v_cvt_pk_bf16_f32 %0, %1, %2" : "=v"(pk1) : "v"(p[8*w+2]), "v"(p[8*w+3])); \
        asm("v_cvt_pk_bf16_f32 %0, %1, %2" : "=v"(pk2) : "v"(p[8*w+4]), "v"(p[8*w+5])); \
        asm("v_cvt_pk_bf16_f32 %0, %1, %2" : "=v"(pk3) : "v"(p[8*w+6]), "v"(p[8*w+7])); \
        u32x2 s0 = __builtin_amdgcn_permlane32_swap(pk0, pk2, false, false);         \
        u32x2 s1 = __builtin_amdgcn_permlane32_swap(pk1, pk3, false, false);         \
        union { unsigned u[4]; bf16x8 v; } apu;                                      \
        apu.u[0] = s0[0]; apu.u[1] = s1[0]; apu.u[2] = s0[1]; apu.u[3] = s1[1];      \
        bf16x8 aP = apu.v;                                                           \
        _Pragma("unroll")                                                            \
        for (int dt = 0; dt < 4; dt++) {                                             \
          bf16x8 vf = *(const bf16x8*)(sc + (BUF) * 16384 + voff[kg][w] + dt * 4096);\
          oacc[dt] = __builtin_amdgcn_mfma_f32_32x32x16_bf16(aP, vf, oacc[dt], 0, 0, 0); \
        }                                                                            \
      }                                                                              \
      __builtin_amdgcn_s_setprio(0);                                                 \
    }                                                                                \
    CFENCE();                                                                        \
    __builtin_amdgcn_s_barrier();   /* protect buf from T+2's prefetch overwrite */  \
    CFENCE();                                                                        \
  }

    for (int tt = 0; tt < 32; tt += 2) {
        ATTN_TILE(0, tt);
        ATTN_TILE(1, tt + 1);
    }
#undef ATTN_TILE

    lsum += __shfl_xor(lsum, 32);    // add other half-lane's keys
    float* ob = out + ((size_t)(b * SEQ + q0)) * (HEADS * ROT) + h * ROT + m;
    #pragma unroll
    for (int r = 0; r < 16; r++) {
        int qrow = (r & 3) + 8 * (r >> 2) + 4 * hl;
        float linv = 1.0f / __shfl(lsum, qrow);
        float* orow = ob + (size_t)qrow * (HEADS * ROT);
        #pragma unroll
        for (int dt = 0; dt < 4; dt++) orow[dt * 32] = oacc[dt][r] * linv;
    }
}

// ---------------------------------------------------------------------------
extern "C" void kernel_launch(void* const* d_in, const int* in_sizes, int n_in,
                              void* d_out, int out_size, void* d_ws, size_t ws_size,
                              hipStream_t stream) {
    (void)in_sizes; (void)n_in; (void)out_size; (void)ws_size;
    const float* x        = (const float*)d_in[0];
    const float* a        = (const float*)d_in[1];
    const float* Wq_x     = (const float*)d_in[2];
    const float* Wkv_x    = (const float*)d_in[3];
    const float* Wq_a     = (const float*)d_in[4];
    const float* Wkv_a    = (const float*)d_in[5];
    const float* qx_scale = (const float*)d_in[6];
    const float* qa_scale = (const float*)d_in[7];
    const float* kx_scale = (const float*)d_in[8];
    const float* ka_scale = (const float*)d_in[9];
    float* out = (float*)d_out;

    unsigned short* Pbf   = (unsigned short*)d_ws;
    unsigned short* qbuf  = Pbf   + (size_t)2 * ROWS * PCOLS;
    unsigned short* kbuf  = qbuf  + (size_t)BATCH * HEADS * SEQ * ROT;
    unsigned short* vbufT = kbuf  + (size_t)BATCH * SEQ * ROT;
    unsigned short* xbf   = vbufT + (size_t)BATCH * SEQ * ROT;
    unsigned short* wbf   = xbf   + (size_t)2 * ROWS * DIM;
    float2*         tbl   = (float2*)(wbf + (size_t)2 * PCOLS * DIM);

    convert_kernel<<<dim3(2752), 256, 0, stream>>>(x, a, Wq_x, Wkv_x, Wq_a, Wkv_a,
                                                   xbf, wbf, tbl);
    mfma_gemm_kernel<<<dim3(32, 9, 2), 256, 0, stream>>>(xbf, wbf, Pbf);
    fuse_kernel<<<dim3(ROWS), 256, 0, stream>>>(Pbf, qx_scale, qa_scale, kx_scale, ka_scale,
                                                tbl, qbuf, kbuf, vbufT);
    attn_kernel<<<dim3(SEQ / 128, HEADS, BATCH), 256, 0, stream>>>(qbuf, kbuf, vbufT, out);
}